// Round 1
// baseline (8510.570 us; speedup 1.0000x reference)
//
#include <hip/hip_runtime.h>
#include <math.h>

#define N_PTS 4096
#define BATCH 4
#define KNN 10

__device__ __forceinline__ bool better(float v1, int i1, float v2, int i2) {
    return (v1 > v2) || (v1 == v2 && i1 < i2);
}

__device__ __forceinline__ unsigned f2key(float x) {
    unsigned u = __float_as_uint(x);
    return (u & 0x80000000u) ? ~u : (u | 0x80000000u);
}
__device__ __forceinline__ float key2f(unsigned k) {
    unsigned u = (k & 0x80000000u) ? (k & 0x7FFFFFFFu) : ~k;
    return __uint_as_float(u);
}

__device__ __forceinline__ float lrelu(float h) { return (h > 0.f) ? h : 0.2f * h; }

// ---------------- squared norms ----------------
__global__ void sq_kernel(const float* __restrict__ x, int xstr, int D,
                          float* __restrict__ sq) {
    int g = blockIdx.x * blockDim.x + threadIdx.x;
    if (g >= BATCH * N_PTS) return;
    const float* row = x + (long)g * xstr;
    float s = 0.f;
    for (int c = 0; c < D; ++c) { float v = row[c]; s += v * v; }
    sq[g] = s;
}

// ---------------- neg-distance tile GEMM (one batch, row chunk of 1024) ----
// dist[(r-row0)*N + c] = 2*dot(x_r,x_c) - sq[r] - sq[c]
__global__ __launch_bounds__(256) void dist_kernel(const float* __restrict__ x,
                                                   const float* __restrict__ sq,
                                                   float* __restrict__ dist,
                                                   int xstr, int D, int row0) {
    __shared__ float As[16][65];
    __shared__ float Bs[16][65];
    int tx = threadIdx.x & 15, ty = threadIdx.x >> 4;
    int r0 = row0 + blockIdx.y * 64;
    int c0 = blockIdx.x * 64;
    float acc[4][4] = {};
    int nk = (D + 15) >> 4;
    for (int kt = 0; kt < nk; ++kt) {
        int k0 = kt * 16;
        for (int e = threadIdx.x; e < 1024; e += 256) {
            int kk = e & 15, r = e >> 4;
            int c = k0 + kk;
            As[kk][r] = (c < D) ? x[(long)(r0 + r) * xstr + c] : 0.f;
        }
        for (int e = threadIdx.x; e < 1024; e += 256) {
            int kk = e & 15, r = e >> 4;
            int c = k0 + kk;
            Bs[kk][r] = (c < D) ? x[(long)(c0 + r) * xstr + c] : 0.f;
        }
        __syncthreads();
        #pragma unroll
        for (int kk = 0; kk < 16; ++kk) {
            float a[4], b[4];
            #pragma unroll
            for (int i = 0; i < 4; ++i) a[i] = As[kk][ty * 4 + i];
            #pragma unroll
            for (int j = 0; j < 4; ++j) b[j] = Bs[kk][tx * 4 + j];
            #pragma unroll
            for (int i = 0; i < 4; ++i)
                #pragma unroll
                for (int j = 0; j < 4; ++j) acc[i][j] += a[i] * b[j];
        }
        __syncthreads();
    }
    #pragma unroll
    for (int i = 0; i < 4; ++i) {
        int r = r0 + ty * 4 + i;
        float sr = sq[r];
        int cb = c0 + tx * 4;
        float4 v;
        v.x = 2.f * acc[i][0] - sr - sq[cb + 0];
        v.y = 2.f * acc[i][1] - sr - sq[cb + 1];
        v.z = 2.f * acc[i][2] - sr - sq[cb + 2];
        v.w = 2.f * acc[i][3] - sr - sq[cb + 3];
        *(float4*)(&dist[(long)(r - row0) * N_PTS + cb]) = v;
    }
}

// ---------------- wave-per-row top-(k+1), drop self ----------------
__global__ __launch_bounds__(256) void topk_kernel(const float* __restrict__ dist,
                                                   int* __restrict__ idxout, int row0) {
    int wave = threadIdx.x >> 6;
    int lane = threadIdx.x & 63;
    int row_local = blockIdx.x * 4 + wave;
    const float* d = dist + (long)row_local * N_PTS;
    float lv[11]; int li[11];
    #pragma unroll
    for (int j = 0; j < 11; ++j) { lv[j] = -INFINITY; li[j] = 0x7FFFFFFF; }
    for (int jj = 0; jj < 64; ++jj) {
        int c = jj * 64 + lane;
        float v = d[c];
        if (better(v, c, lv[10], li[10])) {
            lv[10] = v; li[10] = c;
            #pragma unroll
            for (int j = 10; j > 0; --j) {
                if (better(lv[j], li[j], lv[j - 1], li[j - 1])) {
                    float tv = lv[j]; lv[j] = lv[j - 1]; lv[j - 1] = tv;
                    int ti = li[j]; li[j] = li[j - 1]; li[j - 1] = ti;
                }
            }
        }
    }
    int keep = 0;
    #pragma unroll
    for (int r = 0; r < 11; ++r) {
        float bv = lv[0]; int bi = li[0];
        #pragma unroll
        for (int off = 32; off > 0; off >>= 1) {
            float ov = __shfl_xor(bv, off);
            int oi = __shfl_xor(bi, off);
            if (better(ov, oi, bv, bi)) { bv = ov; bi = oi; }
        }
        if (li[0] == bi) {   // this lane supplied the winner: pop its head
            #pragma unroll
            for (int j = 0; j < 10; ++j) { lv[j] = lv[j + 1]; li[j] = li[j + 1]; }
            lv[10] = -INFINITY; li[10] = 0x7FFFFFFF;
        }
        if (r > 0 && lane == r - 1) keep = bi;
    }
    if (lane < 10) idxout[(long)(row0 + row_local) * KNN + lane] = keep;
}

// ---------------- fused edge conv: gather + MLP + BN + lrelu + max_k ------
// h[kk][o] = dot(nm[kk], w[o][0:DIN]) + dot(ctr, w[o][DIN:2DIN])
template <int DIN, int DOUT, int PTS, int TPP>
__global__ __launch_bounds__(256) void edgeconv_kernel(
    const float* __restrict__ x, int xstr, const int* __restrict__ idx,
    const float* __restrict__ w, const float* __restrict__ gamma,
    const float* __restrict__ beta, float* __restrict__ out, int outoff) {
    constexpr int DP = DIN + 1;
    constexpr int C2 = 2 * DIN;
    __shared__ float ctr[PTS][DP];
    __shared__ float nm[PTS][KNN][DP];
    int p0 = blockIdx.x * PTS;
    for (int e = threadIdx.x; e < PTS * DIN; e += 256) {
        int p = e / DIN, c = e - p * DIN;
        ctr[p][c] = x[(long)(p0 + p) * xstr + c];
    }
    __syncthreads();
    for (int e = threadIdx.x; e < PTS * KNN * DIN; e += 256) {
        int p = e / (KNN * DIN);
        int rem = e - p * (KNN * DIN);
        int kk = rem / DIN, c = rem - kk * DIN;
        int g = p0 + p;
        int b = g >> 12;           // N=4096
        int nb = (b << 12) + idx[(long)g * KNN + kk];
        nm[p][kk][c] = x[(long)nb * xstr + c] - ctr[p][c];
    }
    __syncthreads();
    int p = threadIdx.x / TPP;
    int og = (threadIdx.x % TPP) * 4;
    float gs[4], bt[4];
    #pragma unroll
    for (int j = 0; j < 4; ++j) {
        gs[j] = gamma[og + j] / sqrtf(1.f + 1e-5f);
        bt[j] = beta[og + j];
    }
    float base[4] = {0.f, 0.f, 0.f, 0.f};
    for (int c = 0; c < DIN; ++c) {
        float cv = ctr[p][c];
        #pragma unroll
        for (int j = 0; j < 4; ++j) base[j] += cv * w[(og + j) * C2 + DIN + c];
    }
    float acc[KNN][4];
    #pragma unroll
    for (int kk = 0; kk < KNN; ++kk)
        #pragma unroll
        for (int j = 0; j < 4; ++j) acc[kk][j] = base[j];
    for (int c = 0; c < DIN; ++c) {
        float w4[4];
        #pragma unroll
        for (int j = 0; j < 4; ++j) w4[j] = w[(og + j) * C2 + c];
        #pragma unroll
        for (int kk = 0; kk < KNN; ++kk) {
            float nv = nm[p][kk][c];
            #pragma unroll
            for (int j = 0; j < 4; ++j) acc[kk][j] += nv * w4[j];
        }
    }
    float best[4] = {-INFINITY, -INFINITY, -INFINITY, -INFINITY};
    #pragma unroll
    for (int kk = 0; kk < KNN; ++kk)
        #pragma unroll
        for (int j = 0; j < 4; ++j)
            best[j] = fmaxf(best[j], lrelu(acc[kk][j] * gs[j] + bt[j]));
    #pragma unroll
    for (int j = 0; j < 4; ++j)
        out[(long)(p0 + p) * 512 + outoff + og + j] = best[j];
}

// ---------------- init h5 key buffer ----------------
__global__ void init_h5_kernel(unsigned* __restrict__ h5key) {
    int t = blockIdx.x * blockDim.x + threadIdx.x;
    if (t < BATCH * 1024) h5key[t] = 0u;
}

// ---------------- w5 GEMM + BN + lrelu + max over n ----------------
__global__ __launch_bounds__(256) void w5max_kernel(
    const float* __restrict__ cat, const float* __restrict__ w5,
    const float* __restrict__ g5, const float* __restrict__ b5,
    unsigned* __restrict__ h5key) {
    __shared__ float As[16][65];
    __shared__ float Bs[16][65];
    int b = blockIdx.z;
    int n0 = blockIdx.y * 64, o0 = blockIdx.x * 64;
    int tx = threadIdx.x & 15, ty = threadIdx.x >> 4;
    const float* A = cat + (long)b * N_PTS * 512;
    float acc[4][4] = {};
    for (int kt = 0; kt < 32; ++kt) {
        int k0 = kt * 16;
        for (int e = threadIdx.x; e < 1024; e += 256) {
            int kk = e & 15, r = e >> 4;
            As[kk][r] = A[(long)(n0 + r) * 512 + k0 + kk];
            Bs[kk][r] = w5[(long)(o0 + r) * 512 + k0 + kk];
        }
        __syncthreads();
        #pragma unroll
        for (int kk = 0; kk < 16; ++kk) {
            float a[4], bb[4];
            #pragma unroll
            for (int i = 0; i < 4; ++i) a[i] = As[kk][ty * 4 + i];
            #pragma unroll
            for (int j = 0; j < 4; ++j) bb[j] = Bs[kk][tx * 4 + j];
            #pragma unroll
            for (int i = 0; i < 4; ++i)
                #pragma unroll
                for (int j = 0; j < 4; ++j) acc[i][j] += a[i] * bb[j];
        }
        __syncthreads();
    }
    float colmax[4];
    #pragma unroll
    for (int j = 0; j < 4; ++j) {
        int o = o0 + tx * 4 + j;
        float gsc = g5[o] / sqrtf(1.f + 1e-5f);
        float bto = b5[o];
        float m = -INFINITY;
        #pragma unroll
        for (int i = 0; i < 4; ++i)
            m = fmaxf(m, lrelu(acc[i][j] * gsc + bto));
        colmax[j] = m;
    }
    __syncthreads();
    float* red = &As[0][0];   // reuse as [16][64]
    #pragma unroll
    for (int j = 0; j < 4; ++j) red[ty * 64 + tx * 4 + j] = colmax[j];
    __syncthreads();
    if (threadIdx.x < 64) {
        int col = threadIdx.x;
        float m = -INFINITY;
        #pragma unroll
        for (int t = 0; t < 16; ++t) m = fmaxf(m, red[t * 64 + col]);
        atomicMax(&h5key[b * 1024 + o0 + col], f2key(m));
    }
}

// ---------------- FC head ----------------
__global__ void fc1_kernel(const unsigned* __restrict__ h5key,
                           const float* __restrict__ fw1,
                           const float* __restrict__ fg1,
                           const float* __restrict__ fbt1,
                           float* __restrict__ f1) {
    int o = blockIdx.x * 256 + threadIdx.x;
    int b = blockIdx.y;
    if (o >= 512) return;
    float s = 0.f;
    for (int c = 0; c < 1024; ++c)
        s += key2f(h5key[b * 1024 + c]) * fw1[o * 1024 + c];
    float h = s * (fg1[o] / sqrtf(1.f + 1e-5f)) + fbt1[o];
    f1[b * 512 + o] = lrelu(h);
}

__global__ void fc2_kernel(const float* __restrict__ f1,
                           const float* __restrict__ fw2,
                           const float* __restrict__ fb2,
                           const float* __restrict__ fg2,
                           const float* __restrict__ fbt2,
                           float* __restrict__ f2) {
    int o = threadIdx.x;   // 256
    int b = blockIdx.x;
    float s = fb2[o];
    for (int c = 0; c < 512; ++c) s += f1[b * 512 + c] * fw2[o * 512 + c];
    float h = s * (fg2[o] / sqrtf(1.f + 1e-5f)) + fbt2[o];
    f2[b * 256 + o] = lrelu(h);
}

__global__ void fc3_kernel(const float* __restrict__ f2,
                           const float* __restrict__ fw3,
                           const float* __restrict__ fb3,
                           float* __restrict__ out) {
    int t = threadIdx.x;
    if (t >= BATCH * 3) return;
    int b = t / 3, o = t - b * 3;
    float s = fb3[o];
    for (int c = 0; c < 256; ++c) s += f2[b * 256 + c] * fw3[o * 256 + c];
    out[t] = s;
}

extern "C" void kernel_launch(void* const* d_in, const int* in_sizes, int n_in,
                              void* d_out, int out_size, void* d_ws, size_t ws_size,
                              hipStream_t stream) {
    const float* points = (const float*)d_in[0];
    // d_in[1] = k (always 10)
    const float* w1 = (const float*)d_in[2];
    const float* g1 = (const float*)d_in[3];
    const float* b1 = (const float*)d_in[4];
    const float* w2 = (const float*)d_in[5];
    const float* g2 = (const float*)d_in[6];
    const float* b2 = (const float*)d_in[7];
    const float* w3 = (const float*)d_in[8];
    const float* g3 = (const float*)d_in[9];
    const float* b3 = (const float*)d_in[10];
    const float* w4 = (const float*)d_in[11];
    const float* g4 = (const float*)d_in[12];
    const float* b4 = (const float*)d_in[13];
    const float* w5 = (const float*)d_in[14];
    const float* g5 = (const float*)d_in[15];
    const float* b5 = (const float*)d_in[16];
    const float* fw1 = (const float*)d_in[17];
    const float* fg1 = (const float*)d_in[18];
    const float* fbt1 = (const float*)d_in[19];
    const float* fw2 = (const float*)d_in[20];
    const float* fb2 = (const float*)d_in[21];
    const float* fg2 = (const float*)d_in[22];
    const float* fbt2 = (const float*)d_in[23];
    const float* fw3 = (const float*)d_in[24];
    const float* fb3 = (const float*)d_in[25];

    float* ws = (float*)d_ws;
    float* cat = ws;                                   // 4*4096*512
    float* sq = cat + (long)BATCH * N_PTS * 512;       // 16384
    unsigned* h5key = (unsigned*)(sq + BATCH * N_PTS); // 4096
    float* f1 = (float*)(h5key + BATCH * 1024);        // 2048
    float* f2 = f1 + BATCH * 512;                      // 1024
    int* idxbuf = (int*)(f2 + BATCH * 256);            // 4*4096*10
    float* dist = (float*)(idxbuf + (long)BATCH * N_PTS * KNN); // 1024*4096

    auto knn = [&](const float* xbase, int xstr, int D) {
        sq_kernel<<<64, 256, 0, stream>>>(xbase, xstr, D, sq);
        for (int b = 0; b < BATCH; ++b) {
            const float* xb = xbase + (long)b * N_PTS * xstr;
            const float* sqb = sq + b * N_PTS;
            int* idxb = idxbuf + (long)b * N_PTS * KNN;
            for (int r0 = 0; r0 < N_PTS; r0 += 1024) {
                dist_kernel<<<dim3(64, 16), 256, 0, stream>>>(xb, sqb, dist, xstr, D, r0);
                topk_kernel<<<256, 256, 0, stream>>>(dist, idxb, r0);
            }
        }
    };

    // layer 1: points(3) -> o1 (64) at cat+0
    knn(points, 3, 3);
    edgeconv_kernel<3, 64, 16, 16><<<N_PTS * BATCH / 16, 256, 0, stream>>>(
        points, 3, idxbuf, w1, g1, b1, cat, 0);
    // layer 2: o1(64) -> o2 (64) at cat+64
    knn(cat + 0, 512, 64);
    edgeconv_kernel<64, 64, 16, 16><<<N_PTS * BATCH / 16, 256, 0, stream>>>(
        cat + 0, 512, idxbuf, w2, g2, b2, cat, 64);
    // layer 3: o2(64) -> o3 (128) at cat+128
    knn(cat + 64, 512, 64);
    edgeconv_kernel<64, 128, 8, 32><<<N_PTS * BATCH / 8, 256, 0, stream>>>(
        cat + 64, 512, idxbuf, w3, g3, b3, cat, 128);
    // layer 4: o3(128) -> o4 (256) at cat+256
    knn(cat + 128, 512, 128);
    edgeconv_kernel<128, 256, 4, 64><<<N_PTS * BATCH / 4, 256, 0, stream>>>(
        cat + 128, 512, idxbuf, w4, g4, b4, cat, 256);

    // global feature
    init_h5_kernel<<<16, 256, 0, stream>>>(h5key);
    w5max_kernel<<<dim3(16, 64, BATCH), 256, 0, stream>>>(cat, w5, g5, b5, h5key);

    // FC head
    fc1_kernel<<<dim3(2, BATCH), 256, 0, stream>>>(h5key, fw1, fg1, fbt1, f1);
    fc2_kernel<<<BATCH, 256, 0, stream>>>(f1, fw2, fb2, fg2, fbt2, f2);
    fc3_kernel<<<1, 64, 0, stream>>>(f2, fw3, fb3, (float*)d_out);
}

// Round 2
// 4303.757 us; speedup vs baseline: 1.9775x; 1.9775x over previous
//
#include <hip/hip_runtime.h>
#include <math.h>

#define N_PTS 4096
#define BATCH 4
#define KNN 10

__device__ __forceinline__ bool better(float v1, int i1, float v2, int i2) {
    return (v1 > v2) || (v1 == v2 && i1 < i2);
}

__device__ __forceinline__ unsigned f2key(float x) {
    unsigned u = __float_as_uint(x);
    return (u & 0x80000000u) ? ~u : (u | 0x80000000u);
}
__device__ __forceinline__ float key2f(unsigned k) {
    unsigned u = (k & 0x80000000u) ? (k & 0x7FFFFFFFu) : ~k;
    return __uint_as_float(u);
}

__device__ __forceinline__ float lrelu(float h) { return (h > 0.f) ? h : 0.2f * h; }

// ---------------- squared norms ----------------
__global__ void sq_kernel(const float* __restrict__ x, int xstr, int D,
                          float* __restrict__ sq) {
    int g = blockIdx.x * blockDim.x + threadIdx.x;
    if (g >= BATCH * N_PTS) return;
    const float* row = x + (long)g * xstr;
    float s = 0.f;
    if ((D & 3) == 0) {
        for (int c = 0; c < D; c += 4) {
            float4 v = *(const float4*)&row[c];
            s += v.x * v.x + v.y * v.y + v.z * v.z + v.w * v.w;
        }
    } else {
        for (int c = 0; c < D; ++c) { float v = row[c]; s += v * v; }
    }
    sq[g] = s;
}

// ---------------- neg-distance tile GEMM, 128x128 tile, 8x8/thread --------
// dist[b][(r-row0)*N + c] = 2*dot(x_r,x_c) - sq[r] - sq[c]
__global__ __launch_bounds__(256) void dist_kernel(const float* __restrict__ x,
                                                   const float* __restrict__ sq,
                                                   float* __restrict__ dist,
                                                   int xstr, int D, int row0) {
    __shared__ float As[16][132];
    __shared__ float Bs[16][132];
    int b = blockIdx.z;
    const float* xb = x + (long)b * N_PTS * xstr;
    const float* sqb = sq + b * N_PTS;
    float* db = dist + (long)b * 1024 * N_PTS;
    int r0 = row0 + blockIdx.y * 128;   // global row (within batch)
    int c0 = blockIdx.x * 128;
    int tx = threadIdx.x & 15, ty = threadIdx.x >> 4;
    float acc[8][8] = {};
    int nk = (D + 15) >> 4;
    for (int kt = 0; kt < nk; ++kt) {
        int k0 = kt * 16;
        for (int e = threadIdx.x; e < 2048; e += 256) {
            int kk = e & 15, r = e >> 4;
            int c = k0 + kk;
            As[kk][r] = (c < D) ? xb[(long)(r0 + r) * xstr + c] : 0.f;
            Bs[kk][r] = (c < D) ? xb[(long)(c0 + r) * xstr + c] : 0.f;
        }
        __syncthreads();
        #pragma unroll
        for (int kk = 0; kk < 16; ++kk) {
            float a[8], bb[8];
            *(float4*)&a[0] = *(float4*)&As[kk][ty * 8];
            *(float4*)&a[4] = *(float4*)&As[kk][ty * 8 + 4];
            *(float4*)&bb[0] = *(float4*)&Bs[kk][tx * 8];
            *(float4*)&bb[4] = *(float4*)&Bs[kk][tx * 8 + 4];
            #pragma unroll
            for (int i = 0; i < 8; ++i)
                #pragma unroll
                for (int j = 0; j < 8; ++j) acc[i][j] += a[i] * bb[j];
        }
        __syncthreads();
    }
    #pragma unroll
    for (int i = 0; i < 8; ++i) {
        int lr = blockIdx.y * 128 + ty * 8 + i;       // row within chunk
        float sr = sqb[r0 + ty * 8 + i];
        int cb = c0 + tx * 8;
        float4 v0, v1;
        v0.x = 2.f * acc[i][0] - sr - sqb[cb + 0];
        v0.y = 2.f * acc[i][1] - sr - sqb[cb + 1];
        v0.z = 2.f * acc[i][2] - sr - sqb[cb + 2];
        v0.w = 2.f * acc[i][3] - sr - sqb[cb + 3];
        v1.x = 2.f * acc[i][4] - sr - sqb[cb + 4];
        v1.y = 2.f * acc[i][5] - sr - sqb[cb + 5];
        v1.z = 2.f * acc[i][6] - sr - sqb[cb + 6];
        v1.w = 2.f * acc[i][7] - sr - sqb[cb + 7];
        *(float4*)&db[(long)lr * N_PTS + cb] = v0;
        *(float4*)&db[(long)lr * N_PTS + cb + 4] = v1;
    }
}

// ---------------- wave-per-row top-(k+1), drop self ----------------
__global__ __launch_bounds__(256) void topk_kernel(const float* __restrict__ dist,
                                                   int* __restrict__ idxout, int row0) {
    int b = blockIdx.y;
    int wave = threadIdx.x >> 6;
    int lane = threadIdx.x & 63;
    int row_local = blockIdx.x * 4 + wave;
    const float* d = dist + (long)b * 1024 * N_PTS + (long)row_local * N_PTS;
    float lv[11]; int li[11];
    #pragma unroll
    for (int j = 0; j < 11; ++j) { lv[j] = -INFINITY; li[j] = 0x7FFFFFFF; }
    for (int jj = 0; jj < 64; ++jj) {
        int c = jj * 64 + lane;
        float v = d[c];
        if (better(v, c, lv[10], li[10])) {
            lv[10] = v; li[10] = c;
            #pragma unroll
            for (int j = 10; j > 0; --j) {
                if (better(lv[j], li[j], lv[j - 1], li[j - 1])) {
                    float tv = lv[j]; lv[j] = lv[j - 1]; lv[j - 1] = tv;
                    int ti = li[j]; li[j] = li[j - 1]; li[j - 1] = ti;
                }
            }
        }
    }
    int keep = 0;
    #pragma unroll
    for (int r = 0; r < 11; ++r) {
        float bv = lv[0]; int bi = li[0];
        #pragma unroll
        for (int off = 32; off > 0; off >>= 1) {
            float ov = __shfl_xor(bv, off);
            int oi = __shfl_xor(bi, off);
            if (better(ov, oi, bv, bi)) { bv = ov; bi = oi; }
        }
        if (li[0] == bi) {
            #pragma unroll
            for (int j = 0; j < 10; ++j) { lv[j] = lv[j + 1]; li[j] = li[j + 1]; }
            lv[10] = -INFINITY; li[10] = 0x7FFFFFFF;
        }
        if (r > 0 && lane == r - 1) keep = bi;
    }
    if (lane < 10)
        idxout[((long)b * N_PTS + row0 + row_local) * KNN + lane] = keep;
}

// ---------------- edge conv L1 (DIN=3, scalar path) ----------------
template <int DIN, int DOUT, int PTS, int TPP>
__global__ __launch_bounds__(256) void edgeconv_kernel(
    const float* __restrict__ x, int xstr, const int* __restrict__ idx,
    const float* __restrict__ w, const float* __restrict__ gamma,
    const float* __restrict__ beta, float* __restrict__ out, int outoff) {
    constexpr int DP = DIN + 1;
    constexpr int C2 = 2 * DIN;
    __shared__ float ctr[PTS][DP];
    __shared__ float nm[PTS][KNN][DP];
    int p0 = blockIdx.x * PTS;
    for (int e = threadIdx.x; e < PTS * DIN; e += 256) {
        int p = e / DIN, c = e - p * DIN;
        ctr[p][c] = x[(long)(p0 + p) * xstr + c];
    }
    __syncthreads();
    for (int e = threadIdx.x; e < PTS * KNN * DIN; e += 256) {
        int p = e / (KNN * DIN);
        int rem = e - p * (KNN * DIN);
        int kk = rem / DIN, c = rem - kk * DIN;
        int g = p0 + p;
        int nb = (g & ~(N_PTS - 1)) + idx[(long)g * KNN + kk];
        nm[p][kk][c] = x[(long)nb * xstr + c] - ctr[p][c];
    }
    __syncthreads();
    int p = threadIdx.x / TPP;
    int og = (threadIdx.x % TPP) * 4;
    float gs[4], bt[4];
    #pragma unroll
    for (int j = 0; j < 4; ++j) {
        gs[j] = gamma[og + j] / sqrtf(1.f + 1e-5f);
        bt[j] = beta[og + j];
    }
    float base[4] = {0.f, 0.f, 0.f, 0.f};
    for (int c = 0; c < DIN; ++c) {
        float cv = ctr[p][c];
        #pragma unroll
        for (int j = 0; j < 4; ++j) base[j] += cv * w[(og + j) * C2 + DIN + c];
    }
    float acc[KNN][4];
    #pragma unroll
    for (int kk = 0; kk < KNN; ++kk)
        #pragma unroll
        for (int j = 0; j < 4; ++j) acc[kk][j] = base[j];
    for (int c = 0; c < DIN; ++c) {
        float w4[4];
        #pragma unroll
        for (int j = 0; j < 4; ++j) w4[j] = w[(og + j) * C2 + c];
        #pragma unroll
        for (int kk = 0; kk < KNN; ++kk) {
            float nv = nm[p][kk][c];
            #pragma unroll
            for (int j = 0; j < 4; ++j) acc[kk][j] += nv * w4[j];
        }
    }
    float best[4] = {-INFINITY, -INFINITY, -INFINITY, -INFINITY};
    #pragma unroll
    for (int kk = 0; kk < KNN; ++kk)
        #pragma unroll
        for (int j = 0; j < 4; ++j)
            best[j] = fmaxf(best[j], lrelu(acc[kk][j] * gs[j] + bt[j]));
    #pragma unroll
    for (int j = 0; j < 4; ++j)
        out[(long)(p0 + p) * 512 + outoff + og + j] = best[j];
}

// ---------------- edge conv L2-4: float4 everywhere, base split -----------
template <int DIN, int DOUT, int TP>
__global__ __launch_bounds__(256) void edgeconv2_kernel(
    const float* __restrict__ x, int xstr, const int* __restrict__ idx,
    const float* __restrict__ w, const float* __restrict__ gamma,
    const float* __restrict__ beta, float* __restrict__ out, int outoff) {
    constexpr int TPP = DOUT / 4;    // threads per point
    constexpr int DP = DIN + 4;
    constexpr int C2 = 2 * DIN;
    constexpr int D4 = DIN / 4;
    __shared__ float ctr[TP][DP];
    __shared__ float nm[TP][KNN][DP];
    __shared__ int sidx[TP][KNN];
    int p0 = blockIdx.x * TP;
    for (int e = threadIdx.x; e < TP * KNN; e += 256)
        sidx[e / KNN][e % KNN] = idx[(long)(p0 + e / KNN) * KNN + (e % KNN)];
    for (int e = threadIdx.x; e < TP * D4; e += 256) {
        int p = e / D4, c4 = (e % D4) * 4;
        *(float4*)&ctr[p][c4] = *(const float4*)&x[(long)(p0 + p) * xstr + c4];
    }
    __syncthreads();
    for (int e = threadIdx.x; e < TP * KNN * D4; e += 256) {
        int c4 = (e % D4) * 4;
        int kk = (e / D4) % KNN;
        int p = e / (D4 * KNN);
        int g = p0 + p;
        int nb = (g & ~(N_PTS - 1)) + sidx[p][kk];
        float4 nv = *(const float4*)&x[(long)nb * xstr + c4];
        float4 cv = *(const float4*)&ctr[p][c4];
        float4 r;
        r.x = nv.x - cv.x; r.y = nv.y - cv.y; r.z = nv.z - cv.z; r.w = nv.w - cv.w;
        *(float4*)&nm[p][kk][c4] = r;
    }
    __syncthreads();
    int p = threadIdx.x / TPP;
    int og = (threadIdx.x % TPP) * 4;
    const float* wr0 = w + (long)(og + 0) * C2;
    const float* wr1 = w + (long)(og + 1) * C2;
    const float* wr2 = w + (long)(og + 2) * C2;
    const float* wr3 = w + (long)(og + 3) * C2;
    // base = ctr . w_hi
    float base4[4] = {};
    #pragma unroll 2
    for (int c4 = 0; c4 < DIN; c4 += 4) {
        float4 cv = *(float4*)&ctr[p][c4];
        float4 h0 = *(const float4*)&wr0[DIN + c4];
        float4 h1 = *(const float4*)&wr1[DIN + c4];
        float4 h2 = *(const float4*)&wr2[DIN + c4];
        float4 h3 = *(const float4*)&wr3[DIN + c4];
        base4[0] += cv.x * h0.x + cv.y * h0.y + cv.z * h0.z + cv.w * h0.w;
        base4[1] += cv.x * h1.x + cv.y * h1.y + cv.z * h1.z + cv.w * h1.w;
        base4[2] += cv.x * h2.x + cv.y * h2.y + cv.z * h2.z + cv.w * h2.w;
        base4[3] += cv.x * h3.x + cv.y * h3.y + cv.z * h3.z + cv.w * h3.w;
    }
    float acc[KNN][4] = {};
    #pragma unroll 2
    for (int c4 = 0; c4 < DIN; c4 += 4) {
        float4 l0 = *(const float4*)&wr0[c4];
        float4 l1 = *(const float4*)&wr1[c4];
        float4 l2 = *(const float4*)&wr2[c4];
        float4 l3 = *(const float4*)&wr3[c4];
        #pragma unroll
        for (int kk = 0; kk < KNN; ++kk) {
            float4 nv = *(float4*)&nm[p][kk][c4];
            acc[kk][0] += nv.x * l0.x + nv.y * l0.y + nv.z * l0.z + nv.w * l0.w;
            acc[kk][1] += nv.x * l1.x + nv.y * l1.y + nv.z * l1.z + nv.w * l1.w;
            acc[kk][2] += nv.x * l2.x + nv.y * l2.y + nv.z * l2.z + nv.w * l2.w;
            acc[kk][3] += nv.x * l3.x + nv.y * l3.y + nv.z * l3.z + nv.w * l3.w;
        }
    }
    float gs[4], bt[4];
    #pragma unroll
    for (int j = 0; j < 4; ++j) {
        gs[j] = gamma[og + j] / sqrtf(1.f + 1e-5f);
        bt[j] = beta[og + j];
    }
    float best[4] = {-INFINITY, -INFINITY, -INFINITY, -INFINITY};
    #pragma unroll
    for (int kk = 0; kk < KNN; ++kk)
        #pragma unroll
        for (int j = 0; j < 4; ++j)
            best[j] = fmaxf(best[j], lrelu((acc[kk][j] + base4[j]) * gs[j] + bt[j]));
    float4 o4;
    o4.x = best[0]; o4.y = best[1]; o4.z = best[2]; o4.w = best[3];
    *(float4*)&out[(long)(p0 + p) * 512 + outoff + og] = o4;
}

// ---------------- init h5 key buffer ----------------
__global__ void init_h5_kernel(unsigned* __restrict__ h5key) {
    int t = blockIdx.x * blockDim.x + threadIdx.x;
    if (t < BATCH * 1024) h5key[t] = 0u;
}

// ---------------- w5 GEMM + BN + lrelu + max over n, 128x128 tile ---------
__global__ __launch_bounds__(256) void w5max_kernel(
    const float* __restrict__ cat, const float* __restrict__ w5,
    const float* __restrict__ g5, const float* __restrict__ b5,
    unsigned* __restrict__ h5key) {
    __shared__ float As[16][132];
    __shared__ float Bs[16][132];
    int b = blockIdx.z;
    int n0 = blockIdx.y * 128, o0 = blockIdx.x * 128;
    int tx = threadIdx.x & 15, ty = threadIdx.x >> 4;
    const float* A = cat + (long)b * N_PTS * 512;
    float acc[8][8] = {};
    for (int kt = 0; kt < 32; ++kt) {
        int k0 = kt * 16;
        for (int e = threadIdx.x; e < 2048; e += 256) {
            int kk = e & 15, r = e >> 4;
            As[kk][r] = A[(long)(n0 + r) * 512 + k0 + kk];
            Bs[kk][r] = w5[(long)(o0 + r) * 512 + k0 + kk];
        }
        __syncthreads();
        #pragma unroll
        for (int kk = 0; kk < 16; ++kk) {
            float a[8], bb[8];
            *(float4*)&a[0] = *(float4*)&As[kk][ty * 8];
            *(float4*)&a[4] = *(float4*)&As[kk][ty * 8 + 4];
            *(float4*)&bb[0] = *(float4*)&Bs[kk][tx * 8];
            *(float4*)&bb[4] = *(float4*)&Bs[kk][tx * 8 + 4];
            #pragma unroll
            for (int i = 0; i < 8; ++i)
                #pragma unroll
                for (int j = 0; j < 8; ++j) acc[i][j] += a[i] * bb[j];
        }
        __syncthreads();
    }
    float colmax[8];
    #pragma unroll
    for (int j = 0; j < 8; ++j) {
        int o = o0 + tx * 8 + j;
        float gsc = g5[o] / sqrtf(1.f + 1e-5f);
        float bto = b5[o];
        float m = -INFINITY;
        #pragma unroll
        for (int i = 0; i < 8; ++i)
            m = fmaxf(m, lrelu(acc[i][j] * gsc + bto));
        colmax[j] = m;
    }
    __syncthreads();
    float* red = &As[0][0];   // 2048 floats fits in 16*132
    #pragma unroll
    for (int j = 0; j < 8; ++j) red[ty * 128 + tx * 8 + j] = colmax[j];
    __syncthreads();
    if (threadIdx.x < 128) {
        int col = threadIdx.x;
        float m = -INFINITY;
        #pragma unroll
        for (int t = 0; t < 16; ++t) m = fmaxf(m, red[t * 128 + col]);
        atomicMax(&h5key[b * 1024 + o0 + col], f2key(m));
    }
}

// ---------------- FC head ----------------
__global__ void fc1_kernel(const unsigned* __restrict__ h5key,
                           const float* __restrict__ fw1,
                           const float* __restrict__ fg1,
                           const float* __restrict__ fbt1,
                           float* __restrict__ f1) {
    int o = blockIdx.x * 256 + threadIdx.x;
    int b = blockIdx.y;
    if (o >= 512) return;
    float s = 0.f;
    for (int c = 0; c < 1024; ++c)
        s += key2f(h5key[b * 1024 + c]) * fw1[o * 1024 + c];
    float h = s * (fg1[o] / sqrtf(1.f + 1e-5f)) + fbt1[o];
    f1[b * 512 + o] = lrelu(h);
}

__global__ void fc2_kernel(const float* __restrict__ f1,
                           const float* __restrict__ fw2,
                           const float* __restrict__ fb2,
                           const float* __restrict__ fg2,
                           const float* __restrict__ fbt2,
                           float* __restrict__ f2) {
    int o = threadIdx.x;   // 256
    int b = blockIdx.x;
    float s = fb2[o];
    for (int c = 0; c < 512; ++c) s += f1[b * 512 + c] * fw2[o * 512 + c];
    float h = s * (fg2[o] / sqrtf(1.f + 1e-5f)) + fbt2[o];
    f2[b * 256 + o] = lrelu(h);
}

__global__ void fc3_kernel(const float* __restrict__ f2,
                           const float* __restrict__ fw3,
                           const float* __restrict__ fb3,
                           float* __restrict__ out) {
    int t = threadIdx.x;
    if (t >= BATCH * 3) return;
    int b = t / 3, o = t - b * 3;
    float s = fb3[o];
    for (int c = 0; c < 256; ++c) s += f2[b * 256 + c] * fw3[o * 256 + c];
    out[t] = s;
}

extern "C" void kernel_launch(void* const* d_in, const int* in_sizes, int n_in,
                              void* d_out, int out_size, void* d_ws, size_t ws_size,
                              hipStream_t stream) {
    const float* points = (const float*)d_in[0];
    // d_in[1] = k (always 10)
    const float* w1 = (const float*)d_in[2];
    const float* g1 = (const float*)d_in[3];
    const float* b1 = (const float*)d_in[4];
    const float* w2 = (const float*)d_in[5];
    const float* g2 = (const float*)d_in[6];
    const float* b2 = (const float*)d_in[7];
    const float* w3 = (const float*)d_in[8];
    const float* g3 = (const float*)d_in[9];
    const float* b3 = (const float*)d_in[10];
    const float* w4 = (const float*)d_in[11];
    const float* g4 = (const float*)d_in[12];
    const float* b4 = (const float*)d_in[13];
    const float* w5 = (const float*)d_in[14];
    const float* g5 = (const float*)d_in[15];
    const float* b5 = (const float*)d_in[16];
    const float* fw1 = (const float*)d_in[17];
    const float* fg1 = (const float*)d_in[18];
    const float* fbt1 = (const float*)d_in[19];
    const float* fw2 = (const float*)d_in[20];
    const float* fb2 = (const float*)d_in[21];
    const float* fg2 = (const float*)d_in[22];
    const float* fbt2 = (const float*)d_in[23];
    const float* fw3 = (const float*)d_in[24];
    const float* fb3 = (const float*)d_in[25];

    float* ws = (float*)d_ws;
    float* cat = ws;                                     // 4*4096*512
    float* sq = cat + (long)BATCH * N_PTS * 512;         // 16384
    unsigned* h5key = (unsigned*)(sq + BATCH * N_PTS);   // 4096
    float* f1 = (float*)(h5key + BATCH * 1024);          // 2048
    float* f2 = f1 + BATCH * 512;                        // 1024
    int* idxbuf = (int*)(f2 + BATCH * 256);              // 4*4096*10
    float* dist = (float*)(idxbuf + (long)BATCH * N_PTS * KNN); // 4*1024*4096

    auto knn = [&](const float* xbase, int xstr, int D) {
        sq_kernel<<<64, 256, 0, stream>>>(xbase, xstr, D, sq);
        for (int r0 = 0; r0 < N_PTS; r0 += 1024) {
            dist_kernel<<<dim3(32, 8, BATCH), 256, 0, stream>>>(xbase, sq, dist, xstr, D, r0);
            topk_kernel<<<dim3(256, BATCH), 256, 0, stream>>>(dist, idxbuf, r0);
        }
    };

    // layer 1: points(3) -> o1 (64) at cat+0
    knn(points, 3, 3);
    edgeconv_kernel<3, 64, 16, 16><<<N_PTS * BATCH / 16, 256, 0, stream>>>(
        points, 3, idxbuf, w1, g1, b1, cat, 0);
    // layer 2: o1(64) -> o2 (64) at cat+64
    knn(cat + 0, 512, 64);
    edgeconv2_kernel<64, 64, 16><<<N_PTS * BATCH / 16, 256, 0, stream>>>(
        cat + 0, 512, idxbuf, w2, g2, b2, cat, 64);
    // layer 3: o2(64) -> o3 (128) at cat+128
    knn(cat + 64, 512, 64);
    edgeconv2_kernel<64, 128, 8><<<N_PTS * BATCH / 8, 256, 0, stream>>>(
        cat + 64, 512, idxbuf, w3, g3, b3, cat, 128);
    // layer 4: o3(128) -> o4 (256) at cat+256
    knn(cat + 128, 512, 128);
    edgeconv2_kernel<128, 256, 4><<<N_PTS * BATCH / 4, 256, 0, stream>>>(
        cat + 128, 512, idxbuf, w4, g4, b4, cat, 256);

    // global feature
    init_h5_kernel<<<16, 256, 0, stream>>>(h5key);
    w5max_kernel<<<dim3(8, 32, BATCH), 256, 0, stream>>>(cat, w5, g5, b5, h5key);

    // FC head
    fc1_kernel<<<dim3(2, BATCH), 256, 0, stream>>>(h5key, fw1, fg1, fbt1, f1);
    fc2_kernel<<<BATCH, 256, 0, stream>>>(f1, fw2, fb2, fg2, fbt2, f2);
    fc3_kernel<<<1, 64, 0, stream>>>(f2, fw3, fb3, (float*)d_out);
}

// Round 3
// 3675.027 us; speedup vs baseline: 2.3158x; 1.1711x over previous
//
#include <hip/hip_runtime.h>
#include <math.h>

#define N_PTS 4096
#define BATCH 4
#define KNN 10

__device__ __forceinline__ bool better(float v1, int i1, float v2, int i2) {
    return (v1 > v2) || (v1 == v2 && i1 < i2);
}

__device__ __forceinline__ unsigned f2key(float x) {
    unsigned u = __float_as_uint(x);
    return (u & 0x80000000u) ? ~u : (u | 0x80000000u);
}
__device__ __forceinline__ float key2f(unsigned k) {
    unsigned u = (k & 0x80000000u) ? (k & 0x7FFFFFFFu) : ~k;
    return __uint_as_float(u);
}

__device__ __forceinline__ float lrelu(float h) { return (h > 0.f) ? h : 0.2f * h; }

// ---------------- squared norms ----------------
__global__ void sq_kernel(const float* __restrict__ x, int xstr, int D,
                          float* __restrict__ sq) {
    int g = blockIdx.x * blockDim.x + threadIdx.x;
    if (g >= BATCH * N_PTS) return;
    const float* row = x + (long)g * xstr;
    float s = 0.f;
    if ((D & 3) == 0) {
        for (int c = 0; c < D; c += 4) {
            float4 v = *(const float4*)&row[c];
            s += v.x * v.x + v.y * v.y + v.z * v.z + v.w * v.w;
        }
    } else {
        for (int c = 0; c < D; ++c) { float v = row[c]; s += v * v; }
    }
    sq[g] = s;
}

// ---------------- neg-distance tile GEMM, 128x128 tile, 8x8/thread --------
__global__ __launch_bounds__(256) void dist_kernel(const float* __restrict__ x,
                                                   const float* __restrict__ sq,
                                                   float* __restrict__ dist,
                                                   int xstr, int D, int row0) {
    __shared__ float As[16][132];
    __shared__ float Bs[16][132];
    int b = blockIdx.z;
    const float* xb = x + (long)b * N_PTS * xstr;
    const float* sqb = sq + b * N_PTS;
    float* db = dist + (long)b * 1024 * N_PTS;
    int r0 = row0 + blockIdx.y * 128;
    int c0 = blockIdx.x * 128;
    int tx = threadIdx.x & 15, ty = threadIdx.x >> 4;
    float acc[8][8] = {};
    int nk = (D + 15) >> 4;
    for (int kt = 0; kt < nk; ++kt) {
        int k0 = kt * 16;
        for (int e = threadIdx.x; e < 2048; e += 256) {
            int kk = e & 15, r = e >> 4;
            int c = k0 + kk;
            As[kk][r] = (c < D) ? xb[(long)(r0 + r) * xstr + c] : 0.f;
            Bs[kk][r] = (c < D) ? xb[(long)(c0 + r) * xstr + c] : 0.f;
        }
        __syncthreads();
        #pragma unroll
        for (int kk = 0; kk < 16; ++kk) {
            float a[8], bb[8];
            *(float4*)&a[0] = *(float4*)&As[kk][ty * 8];
            *(float4*)&a[4] = *(float4*)&As[kk][ty * 8 + 4];
            *(float4*)&bb[0] = *(float4*)&Bs[kk][tx * 8];
            *(float4*)&bb[4] = *(float4*)&Bs[kk][tx * 8 + 4];
            #pragma unroll
            for (int i = 0; i < 8; ++i)
                #pragma unroll
                for (int j = 0; j < 8; ++j) acc[i][j] += a[i] * bb[j];
        }
        __syncthreads();
    }
    #pragma unroll
    for (int i = 0; i < 8; ++i) {
        int lr = blockIdx.y * 128 + ty * 8 + i;
        float sr = sqb[r0 + ty * 8 + i];
        int cb = c0 + tx * 8;
        float4 v0, v1;
        v0.x = 2.f * acc[i][0] - sr - sqb[cb + 0];
        v0.y = 2.f * acc[i][1] - sr - sqb[cb + 1];
        v0.z = 2.f * acc[i][2] - sr - sqb[cb + 2];
        v0.w = 2.f * acc[i][3] - sr - sqb[cb + 3];
        v1.x = 2.f * acc[i][4] - sr - sqb[cb + 4];
        v1.y = 2.f * acc[i][5] - sr - sqb[cb + 5];
        v1.z = 2.f * acc[i][6] - sr - sqb[cb + 6];
        v1.w = 2.f * acc[i][7] - sr - sqb[cb + 7];
        *(float4*)&db[(long)lr * N_PTS + cb] = v0;
        *(float4*)&db[(long)lr * N_PTS + cb + 4] = v1;
    }
}

// ---------------- wave-per-row top-(k+1), drop self ----------------
__global__ __launch_bounds__(256) void topk_kernel(const float* __restrict__ dist,
                                                   int* __restrict__ idxout, int row0) {
    int b = blockIdx.y;
    int wave = threadIdx.x >> 6;
    int lane = threadIdx.x & 63;
    int row_local = blockIdx.x * 4 + wave;
    const float* d = dist + (long)b * 1024 * N_PTS + (long)row_local * N_PTS;
    float lv[11]; int li[11];
    #pragma unroll
    for (int j = 0; j < 11; ++j) { lv[j] = -INFINITY; li[j] = 0x7FFFFFFF; }
    for (int jj = 0; jj < 64; ++jj) {
        int c = jj * 64 + lane;
        float v = d[c];
        if (better(v, c, lv[10], li[10])) {
            lv[10] = v; li[10] = c;
            #pragma unroll
            for (int j = 10; j > 0; --j) {
                if (better(lv[j], li[j], lv[j - 1], li[j - 1])) {
                    float tv = lv[j]; lv[j] = lv[j - 1]; lv[j - 1] = tv;
                    int ti = li[j]; li[j] = li[j - 1]; li[j - 1] = ti;
                }
            }
        }
    }
    int keep = 0;
    #pragma unroll
    for (int r = 0; r < 11; ++r) {
        float bv = lv[0]; int bi = li[0];
        #pragma unroll
        for (int off = 32; off > 0; off >>= 1) {
            float ov = __shfl_xor(bv, off);
            int oi = __shfl_xor(bi, off);
            if (better(ov, oi, bv, bi)) { bv = ov; bi = oi; }
        }
        if (li[0] == bi) {
            #pragma unroll
            for (int j = 0; j < 10; ++j) { lv[j] = lv[j + 1]; li[j] = li[j + 1]; }
            lv[10] = -INFINITY; li[10] = 0x7FFFFFFF;
        }
        if (r > 0 && lane == r - 1) keep = bi;
    }
    if (lane < 10)
        idxout[((long)b * N_PTS + row0 + row_local) * KNN + lane] = keep;
}

// ---------------- edge conv L1 (DIN=3, fused path) ----------------
template <int DIN, int DOUT, int PTS, int TPP>
__global__ __launch_bounds__(256) void edgeconv_kernel(
    const float* __restrict__ x, int xstr, const int* __restrict__ idx,
    const float* __restrict__ w, const float* __restrict__ gamma,
    const float* __restrict__ beta, float* __restrict__ out, int outoff) {
    constexpr int DP = DIN + 1;
    constexpr int C2 = 2 * DIN;
    __shared__ float ctr[PTS][DP];
    __shared__ float nm[PTS][KNN][DP];
    int p0 = blockIdx.x * PTS;
    for (int e = threadIdx.x; e < PTS * DIN; e += 256) {
        int p = e / DIN, c = e - p * DIN;
        ctr[p][c] = x[(long)(p0 + p) * xstr + c];
    }
    __syncthreads();
    for (int e = threadIdx.x; e < PTS * KNN * DIN; e += 256) {
        int p = e / (KNN * DIN);
        int rem = e - p * (KNN * DIN);
        int kk = rem / DIN, c = rem - kk * DIN;
        int g = p0 + p;
        int nb = (g & ~(N_PTS - 1)) + idx[(long)g * KNN + kk];
        nm[p][kk][c] = x[(long)nb * xstr + c] - ctr[p][c];
    }
    __syncthreads();
    int p = threadIdx.x / TPP;
    int og = (threadIdx.x % TPP) * 4;
    float gs[4], bt[4];
    #pragma unroll
    for (int j = 0; j < 4; ++j) {
        gs[j] = gamma[og + j] / sqrtf(1.f + 1e-5f);
        bt[j] = beta[og + j];
    }
    float base[4] = {0.f, 0.f, 0.f, 0.f};
    for (int c = 0; c < DIN; ++c) {
        float cv = ctr[p][c];
        #pragma unroll
        for (int j = 0; j < 4; ++j) base[j] += cv * w[(og + j) * C2 + DIN + c];
    }
    float acc[KNN][4];
    #pragma unroll
    for (int kk = 0; kk < KNN; ++kk)
        #pragma unroll
        for (int j = 0; j < 4; ++j) acc[kk][j] = base[j];
    for (int c = 0; c < DIN; ++c) {
        float w4[4];
        #pragma unroll
        for (int j = 0; j < 4; ++j) w4[j] = w[(og + j) * C2 + c];
        #pragma unroll
        for (int kk = 0; kk < KNN; ++kk) {
            float nv = nm[p][kk][c];
            #pragma unroll
            for (int j = 0; j < 4; ++j) acc[kk][j] += nv * w4[j];
        }
    }
    float best[4] = {-INFINITY, -INFINITY, -INFINITY, -INFINITY};
    #pragma unroll
    for (int kk = 0; kk < KNN; ++kk)
        #pragma unroll
        for (int j = 0; j < 4; ++j)
            best[j] = fmaxf(best[j], lrelu(acc[kk][j] * gs[j] + bt[j]));
    #pragma unroll
    for (int j = 0; j < 4; ++j)
        out[(long)(p0 + p) * 512 + outoff + og + j] = best[j];
}

// ---------------- uv GEMM: uv[r][j] = sum_k x[r][k] * Bcat[k][j] ----------
// Bcat[k][j] = (j < DOUT) ? w[j][k] : w[j-DOUT][DIN+k]   (u | v layout)
template <int DIN, int DOUT>
__global__ __launch_bounds__(256) void uvgemm_kernel(
    const float* __restrict__ x, int xoff, const float* __restrict__ w,
    float* __restrict__ uv) {
    constexpr int NC = 2 * DOUT;
    __shared__ float As[16][132];
    __shared__ float Bs[16][132];
    int r0 = blockIdx.y * 128;
    int c0 = blockIdx.x * 128;
    int tx = threadIdx.x & 15, ty = threadIdx.x >> 4;
    float acc[8][8] = {};
    #pragma unroll 1
    for (int kt = 0; kt < DIN / 16; ++kt) {
        int k0 = kt * 16;
        for (int e = threadIdx.x; e < 2048; e += 256) {
            int kk = e & 15, r = e >> 4;
            As[kk][r] = x[(long)(r0 + r) * 512 + xoff + k0 + kk];
            int jg = c0 + r;
            Bs[kk][r] = (jg < DOUT) ? w[(long)jg * (2 * DIN) + k0 + kk]
                                    : w[(long)(jg - DOUT) * (2 * DIN) + DIN + k0 + kk];
        }
        __syncthreads();
        #pragma unroll
        for (int kk = 0; kk < 16; ++kk) {
            float a[8], bb[8];
            *(float4*)&a[0] = *(float4*)&As[kk][ty * 8];
            *(float4*)&a[4] = *(float4*)&As[kk][ty * 8 + 4];
            *(float4*)&bb[0] = *(float4*)&Bs[kk][tx * 8];
            *(float4*)&bb[4] = *(float4*)&Bs[kk][tx * 8 + 4];
            #pragma unroll
            for (int i = 0; i < 8; ++i)
                #pragma unroll
                for (int j = 0; j < 8; ++j) acc[i][j] += a[i] * bb[j];
        }
        __syncthreads();
    }
    #pragma unroll
    for (int i = 0; i < 8; ++i) {
        int r = r0 + ty * 8 + i;
        int cb = c0 + tx * 8;
        *(float4*)&uv[(long)r * NC + cb] = *(float4*)&acc[i][0];
        *(float4*)&uv[(long)r * NC + cb + 4] = *(float4*)&acc[i][4];
    }
}

// ---------------- edge max epilogue: h = u[nb] - u[n] + v[n] --------------
template <int DOUT>
__global__ __launch_bounds__(256) void edgemax_kernel(
    const float* __restrict__ uv, const int* __restrict__ idx,
    const float* __restrict__ gamma, const float* __restrict__ beta,
    float* __restrict__ out, int outoff) {
    constexpr int NC = 2 * DOUT;
    constexpr int TPP = DOUT / 4;
    constexpr int TP = 256 / TPP;
    __shared__ int sidx[TP][KNN];
    int p0 = blockIdx.x * TP;
    for (int e = threadIdx.x; e < TP * KNN; e += 256)
        sidx[e / KNN][e % KNN] = idx[(long)(p0 + e / KNN) * KNN + (e % KNN)];
    __syncthreads();
    int p = threadIdx.x / TPP;
    int og = (threadIdx.x % TPP) * 4;
    int g = p0 + p;
    int base_pt = g & ~(N_PTS - 1);
    const float* rowg = uv + (long)g * NC;
    float4 u_n = *(const float4*)&rowg[og];
    float4 v_n = *(const float4*)&rowg[DOUT + og];
    float c0 = v_n.x - u_n.x, c1 = v_n.y - u_n.y;
    float c2 = v_n.z - u_n.z, c3 = v_n.w - u_n.w;
    const float rs = 1.f / sqrtf(1.f + 1e-5f);
    float gs0 = gamma[og + 0] * rs, gs1 = gamma[og + 1] * rs;
    float gs2 = gamma[og + 2] * rs, gs3 = gamma[og + 3] * rs;
    float bt0 = beta[og + 0], bt1 = beta[og + 1];
    float bt2 = beta[og + 2], bt3 = beta[og + 3];
    float b0 = -INFINITY, b1 = -INFINITY, b2 = -INFINITY, b3 = -INFINITY;
    #pragma unroll
    for (int kk = 0; kk < KNN; ++kk) {
        int nb = base_pt + sidx[p][kk];
        float4 ub = *(const float4*)&uv[(long)nb * NC + og];
        b0 = fmaxf(b0, lrelu((ub.x + c0) * gs0 + bt0));
        b1 = fmaxf(b1, lrelu((ub.y + c1) * gs1 + bt1));
        b2 = fmaxf(b2, lrelu((ub.z + c2) * gs2 + bt2));
        b3 = fmaxf(b3, lrelu((ub.w + c3) * gs3 + bt3));
    }
    float4 o4; o4.x = b0; o4.y = b1; o4.z = b2; o4.w = b3;
    *(float4*)&out[(long)g * 512 + outoff + og] = o4;
}

// ---------------- init h5 key buffer ----------------
__global__ void init_h5_kernel(unsigned* __restrict__ h5key) {
    int t = blockIdx.x * blockDim.x + threadIdx.x;
    if (t < BATCH * 1024) h5key[t] = 0u;
}

// ---------------- w5 GEMM + BN + lrelu + max over n, 128x128 tile ---------
__global__ __launch_bounds__(256) void w5max_kernel(
    const float* __restrict__ cat, const float* __restrict__ w5,
    const float* __restrict__ g5, const float* __restrict__ b5,
    unsigned* __restrict__ h5key) {
    __shared__ float As[16][132];
    __shared__ float Bs[16][132];
    int b = blockIdx.z;
    int n0 = blockIdx.y * 128, o0 = blockIdx.x * 128;
    int tx = threadIdx.x & 15, ty = threadIdx.x >> 4;
    const float* A = cat + (long)b * N_PTS * 512;
    float acc[8][8] = {};
    for (int kt = 0; kt < 32; ++kt) {
        int k0 = kt * 16;
        for (int e = threadIdx.x; e < 2048; e += 256) {
            int kk = e & 15, r = e >> 4;
            As[kk][r] = A[(long)(n0 + r) * 512 + k0 + kk];
            Bs[kk][r] = w5[(long)(o0 + r) * 512 + k0 + kk];
        }
        __syncthreads();
        #pragma unroll
        for (int kk = 0; kk < 16; ++kk) {
            float a[8], bb[8];
            *(float4*)&a[0] = *(float4*)&As[kk][ty * 8];
            *(float4*)&a[4] = *(float4*)&As[kk][ty * 8 + 4];
            *(float4*)&bb[0] = *(float4*)&Bs[kk][tx * 8];
            *(float4*)&bb[4] = *(float4*)&Bs[kk][tx * 8 + 4];
            #pragma unroll
            for (int i = 0; i < 8; ++i)
                #pragma unroll
                for (int j = 0; j < 8; ++j) acc[i][j] += a[i] * bb[j];
        }
        __syncthreads();
    }
    float colmax[8];
    #pragma unroll
    for (int j = 0; j < 8; ++j) {
        int o = o0 + tx * 8 + j;
        float gsc = g5[o] / sqrtf(1.f + 1e-5f);
        float bto = b5[o];
        float m = -INFINITY;
        #pragma unroll
        for (int i = 0; i < 8; ++i)
            m = fmaxf(m, lrelu(acc[i][j] * gsc + bto));
        colmax[j] = m;
    }
    __syncthreads();
    float* red = &As[0][0];
    #pragma unroll
    for (int j = 0; j < 8; ++j) red[ty * 128 + tx * 8 + j] = colmax[j];
    __syncthreads();
    if (threadIdx.x < 128) {
        int col = threadIdx.x;
        float m = -INFINITY;
        #pragma unroll
        for (int t = 0; t < 16; ++t) m = fmaxf(m, red[t * 128 + col]);
        atomicMax(&h5key[b * 1024 + o0 + col], f2key(m));
    }
}

// ---------------- FC head ----------------
__global__ void fc1_kernel(const unsigned* __restrict__ h5key,
                           const float* __restrict__ fw1,
                           const float* __restrict__ fg1,
                           const float* __restrict__ fbt1,
                           float* __restrict__ f1) {
    int o = blockIdx.x * 256 + threadIdx.x;
    int b = blockIdx.y;
    if (o >= 512) return;
    float s = 0.f;
    for (int c = 0; c < 1024; ++c)
        s += key2f(h5key[b * 1024 + c]) * fw1[o * 1024 + c];
    float h = s * (fg1[o] / sqrtf(1.f + 1e-5f)) + fbt1[o];
    f1[b * 512 + o] = lrelu(h);
}

__global__ void fc2_kernel(const float* __restrict__ f1,
                           const float* __restrict__ fw2,
                           const float* __restrict__ fb2,
                           const float* __restrict__ fg2,
                           const float* __restrict__ fbt2,
                           float* __restrict__ f2) {
    int o = threadIdx.x;
    int b = blockIdx.x;
    float s = fb2[o];
    for (int c = 0; c < 512; ++c) s += f1[b * 512 + c] * fw2[o * 512 + c];
    float h = s * (fg2[o] / sqrtf(1.f + 1e-5f)) + fbt2[o];
    f2[b * 256 + o] = lrelu(h);
}

__global__ void fc3_kernel(const float* __restrict__ f2,
                           const float* __restrict__ fw3,
                           const float* __restrict__ fb3,
                           float* __restrict__ out) {
    int t = threadIdx.x;
    if (t >= BATCH * 3) return;
    int b = t / 3, o = t - b * 3;
    float s = fb3[o];
    for (int c = 0; c < 256; ++c) s += f2[b * 256 + c] * fw3[o * 256 + c];
    out[t] = s;
}

extern "C" void kernel_launch(void* const* d_in, const int* in_sizes, int n_in,
                              void* d_out, int out_size, void* d_ws, size_t ws_size,
                              hipStream_t stream) {
    const float* points = (const float*)d_in[0];
    const float* w1 = (const float*)d_in[2];
    const float* g1 = (const float*)d_in[3];
    const float* b1 = (const float*)d_in[4];
    const float* w2 = (const float*)d_in[5];
    const float* g2 = (const float*)d_in[6];
    const float* b2 = (const float*)d_in[7];
    const float* w3 = (const float*)d_in[8];
    const float* g3 = (const float*)d_in[9];
    const float* b3 = (const float*)d_in[10];
    const float* w4 = (const float*)d_in[11];
    const float* g4 = (const float*)d_in[12];
    const float* b4 = (const float*)d_in[13];
    const float* w5 = (const float*)d_in[14];
    const float* g5 = (const float*)d_in[15];
    const float* b5 = (const float*)d_in[16];
    const float* fw1 = (const float*)d_in[17];
    const float* fg1 = (const float*)d_in[18];
    const float* fbt1 = (const float*)d_in[19];
    const float* fw2 = (const float*)d_in[20];
    const float* fb2 = (const float*)d_in[21];
    const float* fg2 = (const float*)d_in[22];
    const float* fbt2 = (const float*)d_in[23];
    const float* fw3 = (const float*)d_in[24];
    const float* fb3 = (const float*)d_in[25];

    float* ws = (float*)d_ws;
    float* cat = ws;                                     // 4*4096*512
    float* sq = cat + (long)BATCH * N_PTS * 512;         // 16384
    unsigned* h5key = (unsigned*)(sq + BATCH * N_PTS);   // 4096
    float* f1 = (float*)(h5key + BATCH * 1024);          // 2048
    float* f2 = f1 + BATCH * 512;                        // 1024
    int* idxbuf = (int*)(f2 + BATCH * 256);              // 4*4096*10
    float* dist = (float*)(idxbuf + (long)BATCH * N_PTS * KNN); // 4*1024*4096
    float* uv = dist;   // alias: dist scratch is free once topk is done

    auto knn = [&](const float* xbase, int xstr, int D) {
        sq_kernel<<<64, 256, 0, stream>>>(xbase, xstr, D, sq);
        for (int r0 = 0; r0 < N_PTS; r0 += 1024) {
            dist_kernel<<<dim3(32, 8, BATCH), 256, 0, stream>>>(xbase, sq, dist, xstr, D, r0);
            topk_kernel<<<dim3(256, BATCH), 256, 0, stream>>>(dist, idxbuf, r0);
        }
    };

    // layer 1: points(3) -> o1 (64) at cat+0 (fused small kernel)
    knn(points, 3, 3);
    edgeconv_kernel<3, 64, 16, 16><<<N_PTS * BATCH / 16, 256, 0, stream>>>(
        points, 3, idxbuf, w1, g1, b1, cat, 0);

    // layer 2: o1(64) -> o2 (64) at cat+64
    knn(cat + 0, 512, 64);
    uvgemm_kernel<64, 64><<<dim3(1, 128), 256, 0, stream>>>(cat, 0, w2, uv);
    edgemax_kernel<64><<<1024, 256, 0, stream>>>(uv, idxbuf, g2, b2, cat, 64);

    // layer 3: o2(64) -> o3 (128) at cat+128
    knn(cat + 64, 512, 64);
    uvgemm_kernel<64, 128><<<dim3(2, 128), 256, 0, stream>>>(cat, 64, w3, uv);
    edgemax_kernel<128><<<2048, 256, 0, stream>>>(uv, idxbuf, g3, b3, cat, 128);

    // layer 4: o3(128) -> o4 (256) at cat+256
    knn(cat + 128, 512, 128);
    uvgemm_kernel<128, 256><<<dim3(4, 128), 256, 0, stream>>>(cat, 128, w4, uv);
    edgemax_kernel<256><<<4096, 256, 0, stream>>>(uv, idxbuf, g4, b4, cat, 256);

    // global feature
    init_h5_kernel<<<16, 256, 0, stream>>>(h5key);
    w5max_kernel<<<dim3(8, 32, BATCH), 256, 0, stream>>>(cat, w5, g5, b5, h5key);

    // FC head
    fc1_kernel<<<dim3(2, BATCH), 256, 0, stream>>>(h5key, fw1, fg1, fbt1, f1);
    fc2_kernel<<<BATCH, 256, 0, stream>>>(f1, fw2, fb2, fg2, fbt2, f2);
    fc3_kernel<<<1, 64, 0, stream>>>(f2, fw3, fb3, (float*)d_out);
}